// Round 11
// baseline (364.520 us; speedup 1.0000x reference)
//
#include <hip/hip_runtime.h>

#define N_NODES 100000
#define N_PAIRS 50000
#define N_EDGES 1600000
#define N_GRAPH 1024
#define NB      196      // buckets of 512 nodes
#define BCAP    10240    // bucket capacity (mean 8192, ~22 sigma slack)
#define PEPT    16       // edges per thread in partition

typedef unsigned short u16;
typedef unsigned int   u32;

__device__ __forceinline__ u16 f2bf(float f) {
    u32 u = __float_as_uint(f);
    u += 0x7FFFu + ((u >> 16) & 1u);
    return (u16)(u >> 16);
}
__device__ __forceinline__ float bf2f(u16 h) { return __uint_as_float(((u32)h) << 16); }
__device__ __forceinline__ float rcpf(float x) { return __builtin_amdgcn_rcpf(x); }
__device__ __forceinline__ float bflo(u32 p) { return __uint_as_float(p << 16); }
__device__ __forceinline__ float bfhi(u32 p) { return __uint_as_float(p & 0xFFFF0000u); }

// ======================= CSR build: bucket partition =======================
__global__ __launch_bounds__(256) void k_partition(const int* __restrict__ ei,
                                                   int* __restrict__ gcnt,
                                                   int* __restrict__ bucketed)
{
    __shared__ int lcnt[NB], gbase[NB], lcur[NB];
    int t = threadIdx.x;
    for (int i = t; i < NB; i += 256) { lcnt[i] = 0; lcur[i] = 0; }
    __syncthreads();

    int ebase = blockIdx.x * (256 * PEPT);
    int pk[PEPT], bk[PEPT];
#pragma unroll
    for (int r = 0; r < PEPT; r++) {
        int e = ebase + r * 256 + t;
        if (e < N_EDGES) {
            int d = ei[N_EDGES + e];
            int s = ei[e];
            int b = d >> 9;
            bk[r] = b;
            pk[r] = ((d & 511) << 17) | s;
            atomicAdd(&lcnt[b], 1);
        } else bk[r] = -1;
    }
    __syncthreads();
    for (int i = t; i < NB; i += 256) gbase[i] = atomicAdd(&gcnt[i], lcnt[i]);
    __syncthreads();
#pragma unroll
    for (int r = 0; r < PEPT; r++) {
        if (bk[r] >= 0) {
            int b = bk[r];
            int pos = gbase[b] + atomicAdd(&lcur[b], 1);
            bucketed[b * BCAP + pos] = pk[r];
        }
    }
}

// one block per bucket: inline scan of gcnt + local CSR in LDS
__global__ __launch_bounds__(512) void k_place(const int* __restrict__ bucketed,
                                               const int* __restrict__ gcnt,
                                               int* __restrict__ csr,
                                               int* __restrict__ starts,
                                               int* __restrict__ cnt)
{
    __shared__ int sb[256];
    __shared__ int scnt[512], sexc[512], scur[512];
    int b = blockIdx.x, t = threadIdx.x;

    if (t < 256) sb[t] = (t < NB) ? gcnt[t] : 0;
    __syncthreads();
#pragma unroll
    for (int off = 1; off < 256; off <<= 1) {
        int u = 0;
        if (t < 256 && t >= off) u = sb[t - off];
        __syncthreads();
        if (t < 256) sb[t] += u;
        __syncthreads();
    }
    int ecnt = gcnt[b];
    int ebase = sb[b] - ecnt;   // exclusive prefix
    const int* bp = bucketed + b * BCAP;

    scnt[t] = 0; scur[t] = 0;
    __syncthreads();
    for (int e = t; e < ecnt; e += 512) atomicAdd(&scnt[bp[e] >> 17], 1);
    __syncthreads();
    int v = scnt[t];
    sexc[t] = v;
    __syncthreads();
#pragma unroll
    for (int off = 1; off < 512; off <<= 1) {
        int u = (t >= off) ? sexc[t - off] : 0;
        __syncthreads();
        sexc[t] += u;
        __syncthreads();
    }
    int excl = sexc[t] - v;
    __syncthreads();
    sexc[t] = excl;
    __syncthreads();

    int node = b * 512 + t;
    if (node < N_NODES) { starts[node] = ebase + excl; cnt[node] = v; }

    for (int e = t; e < ecnt; e += 512) {
        int p = bp[e];
        int ld = p >> 17;
        int pos = ebase + sexc[ld] + atomicAdd(&scur[ld], 1);
        csr[pos] = p & 0x1FFFF;
    }
}

// ======================= Layer 1: ResGated(1 -> 32), x-direct gather =======================
#define EDGE1(XS, ACC) {                                                     \
    ACC.x += fmaf(XS, wv.x, bv4.x) *                                         \
             rcpf(fmaf(ek.x, __expf(-fmaf(XS, wq.x, bq4.x)), 1.0f));         \
    ACC.y += fmaf(XS, wv.y, bv4.y) *                                         \
             rcpf(fmaf(ek.y, __expf(-fmaf(XS, wq.y, bq4.y)), 1.0f));         \
    ACC.z += fmaf(XS, wv.z, bv4.z) *                                         \
             rcpf(fmaf(ek.z, __expf(-fmaf(XS, wq.z, bq4.z)), 1.0f));         \
    ACC.w += fmaf(XS, wv.w, bv4.w) *                                         \
             rcpf(fmaf(ek.w, __expf(-fmaf(XS, wq.w, bq4.w)), 1.0f)); }

__global__ __launch_bounds__(256) void k_gath1(
    const float* __restrict__ x, const int* __restrict__ csr_src,
    const int* __restrict__ starts, const int* __restrict__ cnt,
    const float* __restrict__ Wk, const float* __restrict__ bk,
    const float* __restrict__ Wq, const float* __restrict__ bq,
    const float* __restrict__ Wv, const float* __restrict__ bv,
    const float* __restrict__ Wskip, const float* __restrict__ b,
    u16* __restrict__ h1b)
{
    int tid = blockIdx.x * 256 + threadIdx.x;
    int i = tid >> 3, l = tid & 7;

    float xd = x[i];
    float4 wk = ((const float4*)Wk)[l], bk4 = ((const float4*)bk)[l];
    float4 wq = ((const float4*)Wq)[l], bq4 = ((const float4*)bq)[l];
    float4 wv = ((const float4*)Wv)[l], bv4 = ((const float4*)bv)[l];
    float4 ek;
    ek.x = __expf(-fmaf(xd, wk.x, bk4.x));
    ek.y = __expf(-fmaf(xd, wk.y, bk4.y));
    ek.z = __expf(-fmaf(xd, wk.z, bk4.z));
    ek.w = __expf(-fmaf(xd, wk.w, bk4.w));

    int base = starts[i], deg = cnt[i];
    float4 a0 = make_float4(0.f, 0.f, 0.f, 0.f);
    float4 a1 = make_float4(0.f, 0.f, 0.f, 0.f);
    int e = 0;
    for (; e + 3 < deg; e += 4) {
        int s0 = csr_src[base + e];
        int s1 = csr_src[base + e + 1];
        int s2 = csr_src[base + e + 2];
        int s3 = csr_src[base + e + 3];
        float x0 = x[s0], x1 = x[s1], x2 = x[s2], x3 = x[s3];
        EDGE1(x0, a0) EDGE1(x1, a1) EDGE1(x2, a0) EDGE1(x3, a1)
    }
    for (; e < deg; e++) {
        float x0 = x[csr_src[base + e]];
        EDGE1(x0, a0)
    }
    float4 ws4 = ((const float4*)Wskip)[l];
    float4 bb4 = ((const float4*)b)[l];
    ushort4 o;
    o.x = f2bf(a0.x + a1.x + fmaf(xd, ws4.x, bb4.x));
    o.y = f2bf(a0.y + a1.y + fmaf(xd, ws4.y, bb4.y));
    o.z = f2bf(a0.z + a1.z + fmaf(xd, ws4.z, bb4.z));
    o.w = f2bf(a0.w + a1.w + fmaf(xd, ws4.w, bb4.w));
    ((ushort4*)h1b)[(size_t)i * 8 + l] = o;
}

// dual-node dot: one weight read feeds two FMAs (halves LDS traffic)
__device__ __forceinline__ void dot4x2(const float* __restrict__ h0,
                                       const float* __restrict__ h1,
                                       const float* __restrict__ Wcol, int stride,
                                       float4& a0, float4& a1)
{
    a0 = make_float4(0.f, 0.f, 0.f, 0.f);
    a1 = make_float4(0.f, 0.f, 0.f, 0.f);
#pragma unroll
    for (int k = 0; k < 32; k++) {
        float4 w = *(const float4*)(Wcol + k * stride);
        float h0k = h0[k], h1k = h1[k];
        a0.x = fmaf(h0k, w.x, a0.x);
        a0.y = fmaf(h0k, w.y, a0.y);
        a0.z = fmaf(h0k, w.z, a0.z);
        a0.w = fmaf(h0k, w.w, a0.w);
        a1.x = fmaf(h1k, w.x, a1.x);
        a1.y = fmaf(h1k, w.y, a1.y);
        a1.z = fmaf(h1k, w.z, a1.z);
        a1.w = fmaf(h1k, w.w, a1.w);
    }
}

// unpack a 64-byte bf16 row (4 uint4) into h[32], optional relu
__device__ __forceinline__ void load_row_bf16(const u16* __restrict__ rowb,
                                              size_t i, float* h, bool relu)
{
    const uint4* rp = (const uint4*)rowb + i * 4;
#pragma unroll
    for (int j = 0; j < 4; j++) {
        uint4 q = rp[j];
        float v0 = bflo(q.x), v1 = bfhi(q.x);
        float v2 = bflo(q.y), v3 = bfhi(q.y);
        float v4 = bflo(q.z), v5 = bfhi(q.z);
        float v6 = bflo(q.w), v7 = bfhi(q.w);
        if (relu) {
            v0 = fmaxf(v0, 0.f); v1 = fmaxf(v1, 0.f);
            v2 = fmaxf(v2, 0.f); v3 = fmaxf(v3, 0.f);
            v4 = fmaxf(v4, 0.f); v5 = fmaxf(v5, 0.f);
            v6 = fmaxf(v6, 0.f); v7 = fmaxf(v7, 0.f);
        }
        h[8 * j + 0] = v0; h[8 * j + 1] = v1; h[8 * j + 2] = v2; h[8 * j + 3] = v3;
        h[8 * j + 4] = v4; h[8 * j + 5] = v5; h[8 * j + 6] = v6; h[8 * j + 7] = v7;
    }
}

// ======================= Layer 2: FiLM node-side (f32 LDS weights, 2 nodes/thread) =======================
__global__ __launch_bounds__(256, 2) void k_node2(
    const u16* __restrict__ h1b,
    const float* __restrict__ Wlin, const float* __restrict__ Wfilm,
    const float* __restrict__ bfilm, const float* __restrict__ Wls,
    const float* __restrict__ Wfs,
    u16* __restrict__ skip2b, u16* __restrict__ bg2b, u16* __restrict__ xlb)
{
    __shared__ float sWlin[1024], sWfilm[2048], sWls[1024], sWfs[2048];
    int t = threadIdx.x;
    for (int idx = t; idx < 1024; idx += 256) sWlin[idx] = Wlin[idx];
    for (int idx = t; idx < 2048; idx += 256) sWfilm[idx] = Wfilm[idx];
    for (int idx = t; idx < 1024; idx += 256) sWls[idx] = Wls[idx];
    for (int idx = t; idx < 2048; idx += 256) sWfs[idx] = Wfs[idx];
    __syncthreads();

    int tid = blockIdx.x * 256 + t;
    int pair = tid >> 3, l = tid & 7;
    if (pair >= N_PAIRS) return;
    size_t i0 = (size_t)pair * 2, i1 = i0 + 1;

    float h0[32], h1[32];
    load_row_bf16(h1b, i0, h0, true);
    load_row_bf16(h1b, i1, h1, true);

    // skip path: relu(gamma_s * (h@Wls) + beta_s)
    float4 bs0, bs1, gs0, gs1, ls0, ls1;
    dot4x2(h0, h1, sWfs + l * 4, 64, bs0, bs1);
    dot4x2(h0, h1, sWfs + 32 + l * 4, 64, gs0, gs1);
    dot4x2(h0, h1, sWls + l * 4, 32, ls0, ls1);
    ushort4 sk0, sk1;
    sk0.x = f2bf(fmaxf(fmaf(gs0.x, ls0.x, bs0.x), 0.f));
    sk0.y = f2bf(fmaxf(fmaf(gs0.y, ls0.y, bs0.y), 0.f));
    sk0.z = f2bf(fmaxf(fmaf(gs0.z, ls0.z, bs0.z), 0.f));
    sk0.w = f2bf(fmaxf(fmaf(gs0.w, ls0.w, bs0.w), 0.f));
    sk1.x = f2bf(fmaxf(fmaf(gs1.x, ls1.x, bs1.x), 0.f));
    sk1.y = f2bf(fmaxf(fmaf(gs1.y, ls1.y, bs1.y), 0.f));
    sk1.z = f2bf(fmaxf(fmaf(gs1.z, ls1.z, bs1.z), 0.f));
    sk1.w = f2bf(fmaxf(fmaf(gs1.w, ls1.w, bs1.w), 0.f));
    ((ushort4*)skip2b)[i0 * 8 + l] = sk0;
    ((ushort4*)skip2b)[i1 * 8 + l] = sk1;

    // film beta|gamma (cols l*8 .. l*8+7 of 64)
    float4 bf0 = ((const float4*)bfilm)[l * 2];
    float4 bf1 = ((const float4*)bfilm)[l * 2 + 1];
    float4 f00, f01, f10, f11;
    dot4x2(h0, h1, sWfilm + l * 8, 64, f00, f10);
    dot4x2(h0, h1, sWfilm + l * 8 + 4, 64, f01, f11);
    uint4 pk0, pk1;
    pk0.x = (u32)f2bf(f00.x + bf0.x) | ((u32)f2bf(f00.y + bf0.y) << 16);
    pk0.y = (u32)f2bf(f00.z + bf0.z) | ((u32)f2bf(f00.w + bf0.w) << 16);
    pk0.z = (u32)f2bf(f01.x + bf1.x) | ((u32)f2bf(f01.y + bf1.y) << 16);
    pk0.w = (u32)f2bf(f01.z + bf1.z) | ((u32)f2bf(f01.w + bf1.w) << 16);
    pk1.x = (u32)f2bf(f10.x + bf0.x) | ((u32)f2bf(f10.y + bf0.y) << 16);
    pk1.y = (u32)f2bf(f10.z + bf0.z) | ((u32)f2bf(f10.w + bf0.w) << 16);
    pk1.z = (u32)f2bf(f11.x + bf1.x) | ((u32)f2bf(f11.y + bf1.y) << 16);
    pk1.w = (u32)f2bf(f11.z + bf1.z) | ((u32)f2bf(f11.w + bf1.w) << 16);
    ((uint4*)bg2b)[i0 * 8 + l] = pk0;
    ((uint4*)bg2b)[i1 * 8 + l] = pk1;

    // xl
    float4 x0, x1v;
    dot4x2(h0, h1, sWlin + l * 4, 32, x0, x1v);
    ushort4 xp0, xp1;
    xp0.x = f2bf(x0.x); xp0.y = f2bf(x0.y); xp0.z = f2bf(x0.z); xp0.w = f2bf(x0.w);
    xp1.x = f2bf(x1v.x); xp1.y = f2bf(x1v.y); xp1.z = f2bf(x1v.z); xp1.w = f2bf(x1v.w);
    ((ushort4*)xlb)[i0 * 8 + l] = xp0;
    ((ushort4*)xlb)[i1 * 8 + l] = xp1;
}

#define EDGE_ACC2(U, ACC)                                   \
    ACC.x += fmaxf(fmaf(ga.x, bf2f(U.x), be.x), 0.f);       \
    ACC.y += fmaxf(fmaf(ga.y, bf2f(U.y), be.y), 0.f);       \
    ACC.z += fmaxf(fmaf(ga.z, bf2f(U.z), be.z), 0.f);       \
    ACC.w += fmaxf(fmaf(ga.w, bf2f(U.w), be.w), 0.f);

// FiLM gather: h2 = relu(skip2 + mean relu(gamma_i*xl_s + beta_i)), bf16 out
__global__ __launch_bounds__(256) void k_gath2(
    const int* __restrict__ csr_src, const int* __restrict__ starts,
    const int* __restrict__ cnt,
    const u16* __restrict__ bg2b, const u16* __restrict__ xlb,
    const u16* __restrict__ skip2b, u16* __restrict__ h2b)
{
    int tid = blockIdx.x * 256 + threadIdx.x;
    int i = tid >> 3, l = tid & 7;

    const u16* row = bg2b + (size_t)i * 64;
    ushort4 beu = *(const ushort4*)(row + l * 4);
    ushort4 gau = *(const ushort4*)(row + 32 + l * 4);
    float4 be = make_float4(bf2f(beu.x), bf2f(beu.y), bf2f(beu.z), bf2f(beu.w));
    float4 ga = make_float4(bf2f(gau.x), bf2f(gau.y), bf2f(gau.z), bf2f(gau.w));

    int base = starts[i], deg = cnt[i];
    const ushort4* xp = (const ushort4*)xlb;
    float4 a0 = make_float4(0.f, 0.f, 0.f, 0.f);
    float4 a1 = make_float4(0.f, 0.f, 0.f, 0.f);
    int e = 0;
    for (; e + 7 < deg; e += 8) {
        int s0 = csr_src[base + e];
        int s1 = csr_src[base + e + 1];
        int s2 = csr_src[base + e + 2];
        int s3 = csr_src[base + e + 3];
        int s4 = csr_src[base + e + 4];
        int s5 = csr_src[base + e + 5];
        int s6 = csr_src[base + e + 6];
        int s7 = csr_src[base + e + 7];
        ushort4 u0 = xp[(size_t)s0 * 8 + l];
        ushort4 u1 = xp[(size_t)s1 * 8 + l];
        ushort4 u2 = xp[(size_t)s2 * 8 + l];
        ushort4 u3 = xp[(size_t)s3 * 8 + l];
        ushort4 u4 = xp[(size_t)s4 * 8 + l];
        ushort4 u5 = xp[(size_t)s5 * 8 + l];
        ushort4 u6 = xp[(size_t)s6 * 8 + l];
        ushort4 u7 = xp[(size_t)s7 * 8 + l];
        EDGE_ACC2(u0, a0) EDGE_ACC2(u1, a1) EDGE_ACC2(u2, a0) EDGE_ACC2(u3, a1)
        EDGE_ACC2(u4, a0) EDGE_ACC2(u5, a1) EDGE_ACC2(u6, a0) EDGE_ACC2(u7, a1)
    }
    for (; e < deg; e++) {
        ushort4 u0 = xp[(size_t)csr_src[base + e] * 8 + l];
        EDGE_ACC2(u0, a0)
    }
    float inv = rcpf(fmaxf((float)deg, 1.0f));
    ushort4 sku = ((const ushort4*)skip2b)[(size_t)i * 8 + l];
    ushort4 o;
    o.x = f2bf(fmaxf(fmaf(a0.x + a1.x, inv, bf2f(sku.x)), 0.f));
    o.y = f2bf(fmaxf(fmaf(a0.y + a1.y, inv, bf2f(sku.y)), 0.f));
    o.z = f2bf(fmaxf(fmaf(a0.z + a1.z, inv, bf2f(sku.z)), 0.f));
    o.w = f2bf(fmaxf(fmaf(a0.w + a1.w, inv, bf2f(sku.w)), 0.f));
    ((ushort4*)h2b)[(size_t)i * 8 + l] = o;
}

// ======================= Layer 3 node-side (f32 LDS weights, 2 nodes/thread) =======================
__global__ __launch_bounds__(256, 2) void k_node3(
    const u16* __restrict__ h2b,
    const float* __restrict__ Wk, const float* __restrict__ bk,
    const float* __restrict__ Wq, const float* __restrict__ bq,
    const float* __restrict__ Wv, const float* __restrict__ bv,
    const float* __restrict__ Wskip, const float* __restrict__ b,
    u16* __restrict__ ek3b, u32* __restrict__ qvb, u16* __restrict__ acc3b)
{
    __shared__ float sWk[1024], sWq[1024], sWv[1024], sWs[1024];
    int t = threadIdx.x;
    for (int idx = t; idx < 1024; idx += 256) {
        sWk[idx] = Wk[idx];
        sWq[idx] = Wq[idx];
        sWv[idx] = Wv[idx];
        sWs[idx] = Wskip[idx];
    }
    __syncthreads();

    int tid = blockIdx.x * 256 + t;
    int pair = tid >> 3, l = tid & 7;
    if (pair >= N_PAIRS) return;
    size_t i0 = (size_t)pair * 2, i1 = i0 + 1;

    float h0[32], h1[32];
    load_row_bf16(h2b, i0, h0, false);
    load_row_bf16(h2b, i1, h1, false);

    float4 bk4 = ((const float4*)bk)[l];
    float4 bq4 = ((const float4*)bq)[l];
    float4 bv4 = ((const float4*)bv)[l];
    float4 bb4 = ((const float4*)b)[l];

    float4 kk0, kk1;
    dot4x2(h0, h1, sWk + l * 4, 32, kk0, kk1);
    ushort4 ek0, ek1;
    ek0.x = f2bf(__expf(-(kk0.x + bk4.x)));
    ek0.y = f2bf(__expf(-(kk0.y + bk4.y)));
    ek0.z = f2bf(__expf(-(kk0.z + bk4.z)));
    ek0.w = f2bf(__expf(-(kk0.w + bk4.w)));
    ek1.x = f2bf(__expf(-(kk1.x + bk4.x)));
    ek1.y = f2bf(__expf(-(kk1.y + bk4.y)));
    ek1.z = f2bf(__expf(-(kk1.z + bk4.z)));
    ek1.w = f2bf(__expf(-(kk1.w + bk4.w)));
    ((ushort4*)ek3b)[i0 * 8 + l] = ek0;
    ((ushort4*)ek3b)[i1 * 8 + l] = ek1;

    float4 qq0, qq1, vv0, vv1;
    dot4x2(h0, h1, sWq + l * 4, 32, qq0, qq1);
    dot4x2(h0, h1, sWv + l * 4, 32, vv0, vv1);
    uint4 pk0, pk1;
    pk0.x = (u32)f2bf(__expf(-(qq0.x + bq4.x))) | ((u32)f2bf(__expf(-(qq0.y + bq4.y))) << 16);
    pk0.y = (u32)f2bf(__expf(-(qq0.z + bq4.z))) | ((u32)f2bf(__expf(-(qq0.w + bq4.w))) << 16);
    pk0.z = (u32)f2bf(vv0.x + bv4.x) | ((u32)f2bf(vv0.y + bv4.y) << 16);
    pk0.w = (u32)f2bf(vv0.z + bv4.z) | ((u32)f2bf(vv0.w + bv4.w) << 16);
    pk1.x = (u32)f2bf(__expf(-(qq1.x + bq4.x))) | ((u32)f2bf(__expf(-(qq1.y + bq4.y))) << 16);
    pk1.y = (u32)f2bf(__expf(-(qq1.z + bq4.z))) | ((u32)f2bf(__expf(-(qq1.w + bq4.w))) << 16);
    pk1.z = (u32)f2bf(vv1.x + bv4.x) | ((u32)f2bf(vv1.y + bv4.y) << 16);
    pk1.w = (u32)f2bf(vv1.z + bv4.z) | ((u32)f2bf(vv1.w + bv4.w) << 16);
    ((uint4*)qvb)[i0 * 8 + l] = pk0;
    ((uint4*)qvb)[i1 * 8 + l] = pk1;

    float4 ss0, ss1;
    dot4x2(h0, h1, sWs + l * 4, 32, ss0, ss1);
    ushort4 so0, so1;
    so0.x = f2bf(ss0.x + bb4.x); so0.y = f2bf(ss0.y + bb4.y);
    so0.z = f2bf(ss0.z + bb4.z); so0.w = f2bf(ss0.w + bb4.w);
    so1.x = f2bf(ss1.x + bb4.x); so1.y = f2bf(ss1.y + bb4.y);
    so1.z = f2bf(ss1.z + bb4.z); so1.w = f2bf(ss1.w + bb4.w);
    ((ushort4*)acc3b)[i0 * 8 + l] = so0;
    ((ushort4*)acc3b)[i1 * 8 + l] = so1;
}

// 4 features of one gathered edge: acc += v * rcp(1 + ek*eq)
#define EDGE_ACC(P, ACC)                                                        \
    ACC.x += bf2f((u16)(P.z)) * rcpf(fmaf(ek.x, bf2f((u16)(P.x)), 1.0f));       \
    ACC.y += bf2f((u16)(P.z >> 16)) * rcpf(fmaf(ek.y, bf2f((u16)(P.x >> 16)), 1.0f)); \
    ACC.z += bf2f((u16)(P.w)) * rcpf(fmaf(ek.z, bf2f((u16)(P.y)), 1.0f));       \
    ACC.w += bf2f((u16)(P.w >> 16)) * rcpf(fmaf(ek.w, bf2f((u16)(P.y >> 16)), 1.0f));

// ResGated gather + fused mean-pool
__global__ __launch_bounds__(256) void k_gath3p(
    const int* __restrict__ csr_src, const int* __restrict__ starts,
    const int* __restrict__ cnt,
    const u16* __restrict__ ek3b, const u32* __restrict__ qvb,
    const u16* __restrict__ acc3b, const int* __restrict__ batch,
    float* __restrict__ gsum)
{
    __shared__ float sg[8][32];
    int t = threadIdx.x;
    int tid = blockIdx.x * 256 + t;
    int i = tid >> 3, l = tid & 7;     // grid exact: N*8 == 3125*256

    sg[t >> 5][t & 31] = 0.f;
    int gmin = batch[blockIdx.x * 32];
    __syncthreads();

    ushort4 eku = ((const ushort4*)ek3b)[(size_t)i * 8 + l];
    float4 ek = make_float4(bf2f(eku.x), bf2f(eku.y), bf2f(eku.z), bf2f(eku.w));
    int base = starts[i], deg = cnt[i];
    const uint4* qv = (const uint4*)qvb;
    float4 a0 = make_float4(0.f, 0.f, 0.f, 0.f);
    float4 a1 = make_float4(0.f, 0.f, 0.f, 0.f);
    int e = 0;
    for (; e + 3 < deg; e += 4) {
        int s0 = csr_src[base + e];
        int s1 = csr_src[base + e + 1];
        int s2 = csr_src[base + e + 2];
        int s3 = csr_src[base + e + 3];
        uint4 p0 = qv[(size_t)s0 * 8 + l];
        uint4 p1 = qv[(size_t)s1 * 8 + l];
        uint4 p2 = qv[(size_t)s2 * 8 + l];
        uint4 p3 = qv[(size_t)s3 * 8 + l];
        EDGE_ACC(p0, a0) EDGE_ACC(p1, a1) EDGE_ACC(p2, a0) EDGE_ACC(p3, a1)
    }
    for (; e < deg; e++) {
        uint4 p0 = qv[(size_t)csr_src[base + e] * 8 + l];
        EDGE_ACC(p0, a0)
    }
    ushort4 sku = ((const ushort4*)acc3b)[(size_t)i * 8 + l];
    float4 o = make_float4(bf2f(sku.x) + a0.x + a1.x, bf2f(sku.y) + a0.y + a1.y,
                           bf2f(sku.z) + a0.z + a1.z, bf2f(sku.w) + a0.w + a1.w);

    int g = batch[i];
    int slot = g - gmin;
    if (slot < 8) {
        atomicAdd(&sg[slot][l * 4 + 0], o.x);
        atomicAdd(&sg[slot][l * 4 + 1], o.y);
        atomicAdd(&sg[slot][l * 4 + 2], o.z);
        atomicAdd(&sg[slot][l * 4 + 3], o.w);
    } else {  // defensive fallback
        atomicAdd(&gsum[(size_t)g * 32 + l * 4 + 0], o.x);
        atomicAdd(&gsum[(size_t)g * 32 + l * 4 + 1], o.y);
        atomicAdd(&gsum[(size_t)g * 32 + l * 4 + 2], o.z);
        atomicAdd(&gsum[(size_t)g * 32 + l * 4 + 3], o.w);
    }
    __syncthreads();
    int slot2 = t >> 5, feat = t & 31;
    float v = sg[slot2][feat];
    int gout = gmin + slot2;
    if (v != 0.f && gout < N_GRAPH)
        atomicAdd(&gsum[(size_t)gout * 32 + feat], v);
}

// ======================= classifier (inline segment bounds via bsearch) =======================
__device__ __forceinline__ int lower_bound(const int* __restrict__ a, int key)
{
    int lo = 0, hi = N_NODES;
    while (lo < hi) {
        int mid = (lo + hi) >> 1;
        if (a[mid] < key) lo = mid + 1; else hi = mid;
    }
    return lo;
}

__global__ __launch_bounds__(256) void k_final(
    const float* __restrict__ gsum, const int* __restrict__ batch,
    const float* __restrict__ linW, const float* __restrict__ linb,
    float* __restrict__ out)
{
    int tid = blockIdx.x * 256 + threadIdx.x;
    if (tid >= N_GRAPH * 10) return;
    int g = tid / 10, c = tid % 10;
    int s = lower_bound(batch, g);
    int e = lower_bound(batch, g + 1);
    float inv = rcpf(fmaxf((float)(e - s), 1.0f));
    const float* gr = gsum + (size_t)g * 32;
    float a = 0.f;
#pragma unroll
    for (int k = 0; k < 32; k++) a = fmaf(gr[k], linW[k * 10 + c], a);
    out[tid] = fmaf(a, inv, linb[c]);
}

extern "C" void kernel_launch(void* const* d_in, const int* in_sizes, int n_in,
                              void* d_out, int out_size, void* d_ws, size_t ws_size,
                              hipStream_t stream)
{
    const float* x      = (const float*)d_in[0];
    const int*   ei     = (const int*)d_in[1];
    const int*   batch  = (const int*)d_in[2];
    const float* c1_Wk   = (const float*)d_in[4];
    const float* c1_bk   = (const float*)d_in[5];
    const float* c1_Wq   = (const float*)d_in[6];
    const float* c1_bq   = (const float*)d_in[7];
    const float* c1_Wv   = (const float*)d_in[8];
    const float* c1_bv   = (const float*)d_in[9];
    const float* c1_Wsk  = (const float*)d_in[10];
    const float* c1_b    = (const float*)d_in[11];
    const float* c2_Wlin = (const float*)d_in[12];
    const float* c2_Wfilm= (const float*)d_in[13];
    const float* c2_bfilm= (const float*)d_in[14];
    const float* c2_Wls  = (const float*)d_in[15];
    const float* c2_Wfs  = (const float*)d_in[16];
    const float* c3_Wk   = (const float*)d_in[17];
    const float* c3_bk   = (const float*)d_in[18];
    const float* c3_Wq   = (const float*)d_in[19];
    const float* c3_bq   = (const float*)d_in[20];
    const float* c3_Wv   = (const float*)d_in[21];
    const float* c3_bv   = (const float*)d_in[22];
    const float* c3_Wsk  = (const float*)d_in[23];
    const float* c3_b    = (const float*)d_in[24];
    const float* lin_W   = (const float*)d_in[25];
    const float* lin_b   = (const float*)d_in[26];
    float* out = (float*)d_out;

    const size_t N = N_NODES;

    // ---- workspace layout ----
    int*   gcnt    = (int*)d_ws;                    // 256 (zeroed)
    float* gsum    = (float*)(gcnt + 256);          // G*32 (zeroed, same memset)
    int*   bucketed= (int*)(gsum + N_GRAPH * 32);   // NB*BCAP
    int*   icsr    = bucketed + NB * BCAP;          // E
    int*   istarts = icsr + N_EDGES;                // N
    int*   icnt    = istarts + N;                   // N
    u16*   h1b     = (u16*)(icnt + N);              // N*32 bf16 (reused as h2b)
    u16*   skip2b  = h1b + N * 32;                  // N*32 bf16 (reused as ek3b)
    u16*   bg2b    = skip2b + N * 32;               // N*64 bf16 (reused as qvb)
    u16*   xlb     = bg2b + N * 64;                 // N*32 bf16
    u16*   acc3b   = xlb + N * 32;                  // N*32 bf16

    hipMemsetAsync(gcnt, 0, 256 * sizeof(int) + N_GRAPH * 32 * sizeof(float), stream);

    const int TB = 256;
    int gPart  = (N_EDGES + 256 * PEPT - 1) / (256 * PEPT);  // 391
    int gNode8 = (N_NODES * 8) / TB;                         // 3125 exact
    int gPair8 = (N_PAIRS * 8 + TB - 1) / TB;                // 1563
    int gFin   = (N_GRAPH * 10 + TB - 1) / TB;               // 40

    // CSR build (scan folded into k_place)
    k_partition<<<gPart, TB, 0, stream>>>(ei, gcnt, bucketed);
    k_place<<<NB, 512, 0, stream>>>(bucketed, gcnt, icsr, istarts, icnt);

    // Layer 1: x-direct gather, bf16 out
    k_gath1<<<gNode8, TB, 0, stream>>>(x, icsr, istarts, icnt,
                                       c1_Wk, c1_bk, c1_Wq, c1_bq,
                                       c1_Wv, c1_bv, c1_Wsk, c1_b, h1b);
    // Layer 2 (FiLM, f32 LDS weights, 2 nodes/thread)
    k_node2<<<gPair8, TB, 0, stream>>>(h1b, c2_Wlin, c2_Wfilm, c2_bfilm,
                                       c2_Wls, c2_Wfs, skip2b, bg2b, xlb);
    u16* h2b = h1b;
    k_gath2<<<gNode8, TB, 0, stream>>>(icsr, istarts, icnt, bg2b, xlb, skip2b, h2b);
    // Layer 3 (ResGated, f32 LDS weights, 2 nodes/thread) + fused mean-pool
    u16* ek3b = skip2b;
    u32* qvb  = (u32*)bg2b;
    k_node3<<<gPair8, TB, 0, stream>>>(h2b, c3_Wk, c3_bk, c3_Wq, c3_bq,
                                       c3_Wv, c3_bv, c3_Wsk, c3_b,
                                       ek3b, qvb, acc3b);
    k_gath3p<<<gNode8, TB, 0, stream>>>(icsr, istarts, icnt, ek3b, qvb, acc3b,
                                        batch, gsum);
    // classifier
    k_final<<<gFin, TB, 0, stream>>>(gsum, batch, lin_W, lin_b, out);
}

// Round 12
// 291.546 us; speedup vs baseline: 1.2503x; 1.2503x over previous
//
#include <hip/hip_runtime.h>

#define N_NODES 100000
#define N_EDGES 1600000
#define N_GRAPH 1024
#define NB      196      // buckets of 512 nodes
#define BCAP    10240    // bucket capacity (mean 8192, ~22 sigma slack)
#define PEPT    16       // edges per thread in partition

typedef unsigned short u16;
typedef unsigned int   u32;
typedef short bf16x8 __attribute__((ext_vector_type(8)));
typedef float f32x4  __attribute__((ext_vector_type(4)));

__device__ __forceinline__ u16 f2bf(float f) {
    u32 u = __float_as_uint(f);
    u += 0x7FFFu + ((u >> 16) & 1u);
    return (u16)(u >> 16);
}
__device__ __forceinline__ float bf2f(u16 h) { return __uint_as_float(((u32)h) << 16); }
__device__ __forceinline__ float rcpf(float x) { return __builtin_amdgcn_rcpf(x); }
__device__ __forceinline__ float bflo(u32 p) { return __uint_as_float(p << 16); }
__device__ __forceinline__ float bfhi(u32 p) { return __uint_as_float(p & 0xFFFF0000u); }

// ======================= CSR build: bucket partition =======================
__global__ __launch_bounds__(256) void k_partition(const int* __restrict__ ei,
                                                   int* __restrict__ gcnt,
                                                   int* __restrict__ bucketed)
{
    __shared__ int lcnt[NB], gbase[NB], lcur[NB];
    int t = threadIdx.x;
    for (int i = t; i < NB; i += 256) { lcnt[i] = 0; lcur[i] = 0; }
    __syncthreads();

    int ebase = blockIdx.x * (256 * PEPT);
    int pk[PEPT], bk[PEPT];
#pragma unroll
    for (int r = 0; r < PEPT; r++) {
        int e = ebase + r * 256 + t;
        if (e < N_EDGES) {
            int d = ei[N_EDGES + e];
            int s = ei[e];
            int b = d >> 9;
            bk[r] = b;
            pk[r] = ((d & 511) << 17) | s;
            atomicAdd(&lcnt[b], 1);
        } else bk[r] = -1;
    }
    __syncthreads();
    for (int i = t; i < NB; i += 256) gbase[i] = atomicAdd(&gcnt[i], lcnt[i]);
    __syncthreads();
#pragma unroll
    for (int r = 0; r < PEPT; r++) {
        if (bk[r] >= 0) {
            int b = bk[r];
            int pos = gbase[b] + atomicAdd(&lcur[b], 1);
            bucketed[b * BCAP + pos] = pk[r];
        }
    }
}

// one block per bucket: inline scan of gcnt + local CSR in LDS
__global__ __launch_bounds__(512) void k_place(const int* __restrict__ bucketed,
                                               const int* __restrict__ gcnt,
                                               int* __restrict__ csr,
                                               int* __restrict__ starts,
                                               int* __restrict__ cnt)
{
    __shared__ int sb[256];
    __shared__ int scnt[512], sexc[512], scur[512];
    int b = blockIdx.x, t = threadIdx.x;

    if (t < 256) sb[t] = (t < NB) ? gcnt[t] : 0;
    __syncthreads();
#pragma unroll
    for (int off = 1; off < 256; off <<= 1) {
        int u = 0;
        if (t < 256 && t >= off) u = sb[t - off];
        __syncthreads();
        if (t < 256) sb[t] += u;
        __syncthreads();
    }
    int ecnt = gcnt[b];
    int ebase = sb[b] - ecnt;   // exclusive prefix
    const int* bp = bucketed + b * BCAP;

    scnt[t] = 0; scur[t] = 0;
    __syncthreads();
    for (int e = t; e < ecnt; e += 512) atomicAdd(&scnt[bp[e] >> 17], 1);
    __syncthreads();
    int v = scnt[t];
    sexc[t] = v;
    __syncthreads();
#pragma unroll
    for (int off = 1; off < 512; off <<= 1) {
        int u = (t >= off) ? sexc[t - off] : 0;
        __syncthreads();
        sexc[t] += u;
        __syncthreads();
    }
    int excl = sexc[t] - v;
    __syncthreads();
    sexc[t] = excl;
    __syncthreads();

    int node = b * 512 + t;
    if (node < N_NODES) { starts[node] = ebase + excl; cnt[node] = v; }

    for (int e = t; e < ecnt; e += 512) {
        int p = bp[e];
        int ld = p >> 17;
        int pos = ebase + sexc[ld] + atomicAdd(&scur[ld], 1);
        csr[pos] = p & 0x1FFFF;
    }
}

// ======================= Layer 1: ResGated(1 -> 32), x-direct gather =======================
#define EDGE1(XS, ACC) {                                                     \
    ACC.x += fmaf(XS, wv.x, bv4.x) *                                         \
             rcpf(fmaf(ek.x, __expf(-fmaf(XS, wq.x, bq4.x)), 1.0f));         \
    ACC.y += fmaf(XS, wv.y, bv4.y) *                                         \
             rcpf(fmaf(ek.y, __expf(-fmaf(XS, wq.y, bq4.y)), 1.0f));         \
    ACC.z += fmaf(XS, wv.z, bv4.z) *                                         \
             rcpf(fmaf(ek.z, __expf(-fmaf(XS, wq.z, bq4.z)), 1.0f));         \
    ACC.w += fmaf(XS, wv.w, bv4.w) *                                         \
             rcpf(fmaf(ek.w, __expf(-fmaf(XS, wq.w, bq4.w)), 1.0f)); }

// NOTE: stores relu(h1) — layer 2 only ever consumes relu(h1)
__global__ __launch_bounds__(256) void k_gath1(
    const float* __restrict__ x, const int* __restrict__ csr_src,
    const int* __restrict__ starts, const int* __restrict__ cnt,
    const float* __restrict__ Wk, const float* __restrict__ bk,
    const float* __restrict__ Wq, const float* __restrict__ bq,
    const float* __restrict__ Wv, const float* __restrict__ bv,
    const float* __restrict__ Wskip, const float* __restrict__ b,
    u16* __restrict__ h1b)
{
    int tid = blockIdx.x * 256 + threadIdx.x;
    int i = tid >> 3, l = tid & 7;

    float xd = x[i];
    float4 wk = ((const float4*)Wk)[l], bk4 = ((const float4*)bk)[l];
    float4 wq = ((const float4*)Wq)[l], bq4 = ((const float4*)bq)[l];
    float4 wv = ((const float4*)Wv)[l], bv4 = ((const float4*)bv)[l];
    float4 ek;
    ek.x = __expf(-fmaf(xd, wk.x, bk4.x));
    ek.y = __expf(-fmaf(xd, wk.y, bk4.y));
    ek.z = __expf(-fmaf(xd, wk.z, bk4.z));
    ek.w = __expf(-fmaf(xd, wk.w, bk4.w));

    int base = starts[i], deg = cnt[i];
    float4 a0 = make_float4(0.f, 0.f, 0.f, 0.f);
    float4 a1 = make_float4(0.f, 0.f, 0.f, 0.f);
    int e = 0;
    for (; e + 3 < deg; e += 4) {
        int s0 = csr_src[base + e];
        int s1 = csr_src[base + e + 1];
        int s2 = csr_src[base + e + 2];
        int s3 = csr_src[base + e + 3];
        float x0 = x[s0], x1 = x[s1], x2 = x[s2], x3 = x[s3];
        EDGE1(x0, a0) EDGE1(x1, a1) EDGE1(x2, a0) EDGE1(x3, a1)
    }
    for (; e < deg; e++) {
        float x0 = x[csr_src[base + e]];
        EDGE1(x0, a0)
    }
    float4 ws4 = ((const float4*)Wskip)[l];
    float4 bb4 = ((const float4*)b)[l];
    ushort4 o;
    o.x = f2bf(fmaxf(a0.x + a1.x + fmaf(xd, ws4.x, bb4.x), 0.f));
    o.y = f2bf(fmaxf(a0.y + a1.y + fmaf(xd, ws4.y, bb4.y), 0.f));
    o.z = f2bf(fmaxf(a0.z + a1.z + fmaf(xd, ws4.z, bb4.z), 0.f));
    o.w = f2bf(fmaxf(a0.w + a1.w + fmaf(xd, ws4.w, bb4.w), 0.f));
    ((ushort4*)h1b)[(size_t)i * 8 + l] = o;
}

__device__ __forceinline__ float4 dot4(const float* __restrict__ h,
                                       const float* __restrict__ Wcol, int stride)
{
    float4 a = make_float4(0.f, 0.f, 0.f, 0.f);
#pragma unroll
    for (int k = 0; k < 32; k++) {
        float4 w = *(const float4*)(Wcol + k * stride);
        float hk = h[k];
        a.x = fmaf(hk, w.x, a.x);
        a.y = fmaf(hk, w.y, a.y);
        a.z = fmaf(hk, w.z, a.z);
        a.w = fmaf(hk, w.w, a.w);
    }
    return a;
}

// unpack a 64-byte bf16 row (4 uint4) into h[32], optional relu
__device__ __forceinline__ void load_row_bf16(const u16* __restrict__ rowb,
                                              size_t i, float* h, bool relu)
{
    const uint4* rp = (const uint4*)rowb + i * 4;
#pragma unroll
    for (int j = 0; j < 4; j++) {
        uint4 q = rp[j];
        float v0 = bflo(q.x), v1 = bfhi(q.x);
        float v2 = bflo(q.y), v3 = bfhi(q.y);
        float v4 = bflo(q.z), v5 = bfhi(q.z);
        float v6 = bflo(q.w), v7 = bfhi(q.w);
        if (relu) {
            v0 = fmaxf(v0, 0.f); v1 = fmaxf(v1, 0.f);
            v2 = fmaxf(v2, 0.f); v3 = fmaxf(v3, 0.f);
            v4 = fmaxf(v4, 0.f); v5 = fmaxf(v5, 0.f);
            v6 = fmaxf(v6, 0.f); v7 = fmaxf(v7, 0.f);
        }
        h[8 * j + 0] = v0; h[8 * j + 1] = v1; h[8 * j + 2] = v2; h[8 * j + 3] = v3;
        h[8 * j + 4] = v4; h[8 * j + 5] = v5; h[8 * j + 6] = v6; h[8 * j + 7] = v7;
    }
}

// ======================= node2 weight prep: B-fragment-ordered bf16 =======================
// 12 tiles of 16 cols: [ls(2) | beta_s(2) | gamma_s(2) | xl(2) | beta(2) | gamma(2)]
// frag elem: tile t, lane l, j -> B[k=(l>>4)*8+j][n=l&15]
__global__ __launch_bounds__(256) void k_prepw2(
    const float* __restrict__ Wlin, const float* __restrict__ Wfilm,
    const float* __restrict__ Wls, const float* __restrict__ Wfs,
    u16* __restrict__ wbuf)
{
    for (int idx = threadIdx.x; idx < 12 * 512; idx += 256) {
        int t = idx >> 9, rem = idx & 511;
        int l = rem >> 3, j = rem & 7;
        int k = ((l >> 4) << 3) + j, n = l & 15;
        float v;
        if      (t < 2)  v = Wls [k * 32 + t * 16 + n];
        else if (t < 4)  v = Wfs [k * 64 + (t - 2) * 16 + n];
        else if (t < 6)  v = Wfs [k * 64 + 32 + (t - 4) * 16 + n];
        else if (t < 8)  v = Wlin[k * 32 + (t - 6) * 16 + n];
        else if (t < 10) v = Wfilm[k * 64 + (t - 8) * 16 + n];
        else             v = Wfilm[k * 64 + 32 + (t - 10) * 16 + n];
        wbuf[idx] = f2bf(v);
    }
}

// ======================= Layer 2 node-side via MFMA =======================
// wave = 16 nodes; A-frag = uint4 #quad of node's relu'd h1 row; 12 MFMAs
__global__ __launch_bounds__(256) void k_node2m(
    const u16* __restrict__ h1b, const u16* __restrict__ wbuf,
    const float* __restrict__ bfilm,
    u16* __restrict__ skip2b, u16* __restrict__ bg2b, u16* __restrict__ xlb)
{
    int lane = threadIdx.x & 63, w = threadIdx.x >> 6;
    int nb = blockIdx.x * 64 + w * 16;
    int quad = lane >> 4, c = lane & 15;

    int ia = nb + c;
    if (ia >= N_NODES) ia = N_NODES - 1;
    uint4 aq = ((const uint4*)h1b)[(size_t)ia * 4 + quad];
    bf16x8 a = *(bf16x8*)&aq;

    const uint4* wp = (const uint4*)wbuf;
    f32x4 z = {0.f, 0.f, 0.f, 0.f};

    // ---- group 1: ls, beta_s, gamma_s -> skip ----
    uint4 q0 = wp[0 * 64 + lane], q1 = wp[1 * 64 + lane];
    uint4 q2 = wp[2 * 64 + lane], q3 = wp[3 * 64 + lane];
    uint4 q4 = wp[4 * 64 + lane], q5 = wp[5 * 64 + lane];
    f32x4 dls0 = __builtin_amdgcn_mfma_f32_16x16x32_bf16(a, *(bf16x8*)&q0, z, 0, 0, 0);
    f32x4 dls1 = __builtin_amdgcn_mfma_f32_16x16x32_bf16(a, *(bf16x8*)&q1, z, 0, 0, 0);
    f32x4 dbs0 = __builtin_amdgcn_mfma_f32_16x16x32_bf16(a, *(bf16x8*)&q2, z, 0, 0, 0);
    f32x4 dbs1 = __builtin_amdgcn_mfma_f32_16x16x32_bf16(a, *(bf16x8*)&q3, z, 0, 0, 0);
    f32x4 dgs0 = __builtin_amdgcn_mfma_f32_16x16x32_bf16(a, *(bf16x8*)&q4, z, 0, 0, 0);
    f32x4 dgs1 = __builtin_amdgcn_mfma_f32_16x16x32_bf16(a, *(bf16x8*)&q5, z, 0, 0, 0);
#pragma unroll
    for (int r = 0; r < 4; r++) {
        int node = nb + quad * 4 + r;
        if (node < N_NODES) {
            u16* srow = skip2b + (size_t)node * 32;
            srow[c]      = f2bf(fmaxf(fmaf(dgs0[r], dls0[r], dbs0[r]), 0.f));
            srow[16 + c] = f2bf(fmaxf(fmaf(dgs1[r], dls1[r], dbs1[r]), 0.f));
        }
    }

    // ---- group 2: xl, beta, gamma ----
    uint4 q6 = wp[6 * 64 + lane], q7 = wp[7 * 64 + lane];
    uint4 q8 = wp[8 * 64 + lane], q9 = wp[9 * 64 + lane];
    uint4 qa = wp[10 * 64 + lane], qb = wp[11 * 64 + lane];
    f32x4 dxl0 = __builtin_amdgcn_mfma_f32_16x16x32_bf16(a, *(bf16x8*)&q6, z, 0, 0, 0);
    f32x4 dxl1 = __builtin_amdgcn_mfma_f32_16x16x32_bf16(a, *(bf16x8*)&q7, z, 0, 0, 0);
    f32x4 dbe0 = __builtin_amdgcn_mfma_f32_16x16x32_bf16(a, *(bf16x8*)&q8, z, 0, 0, 0);
    f32x4 dbe1 = __builtin_amdgcn_mfma_f32_16x16x32_bf16(a, *(bf16x8*)&q9, z, 0, 0, 0);
    f32x4 dga0 = __builtin_amdgcn_mfma_f32_16x16x32_bf16(a, *(bf16x8*)&qa, z, 0, 0, 0);
    f32x4 dga1 = __builtin_amdgcn_mfma_f32_16x16x32_bf16(a, *(bf16x8*)&qb, z, 0, 0, 0);

    float bf0 = bfilm[c], bf1 = bfilm[16 + c];
    float bf2 = bfilm[32 + c], bf3 = bfilm[48 + c];
#pragma unroll
    for (int r = 0; r < 4; r++) {
        int node = nb + quad * 4 + r;
        if (node < N_NODES) {
            u16* xrow = xlb + (size_t)node * 32;
            xrow[c]      = f2bf(dxl0[r]);
            xrow[16 + c] = f2bf(dxl1[r]);
            u16* brow = bg2b + (size_t)node * 64;
            brow[c]      = f2bf(dbe0[r] + bf0);
            brow[16 + c] = f2bf(dbe1[r] + bf1);
            brow[32 + c] = f2bf(dga0[r] + bf2);
            brow[48 + c] = f2bf(dga1[r] + bf3);
        }
    }
}

#define EDGE_ACC2(U, ACC)                                   \
    ACC.x += fmaxf(fmaf(ga.x, bf2f(U.x), be.x), 0.f);       \
    ACC.y += fmaxf(fmaf(ga.y, bf2f(U.y), be.y), 0.f);       \
    ACC.z += fmaxf(fmaf(ga.z, bf2f(U.z), be.z), 0.f);       \
    ACC.w += fmaxf(fmaf(ga.w, bf2f(U.w), be.w), 0.f);

// FiLM gather: h2 = relu(skip2 + mean relu(gamma_i*xl_s + beta_i)), bf16 out
__global__ __launch_bounds__(256) void k_gath2(
    const int* __restrict__ csr_src, const int* __restrict__ starts,
    const int* __restrict__ cnt,
    const u16* __restrict__ bg2b, const u16* __restrict__ xlb,
    const u16* __restrict__ skip2b, u16* __restrict__ h2b)
{
    int tid = blockIdx.x * 256 + threadIdx.x;
    int i = tid >> 3, l = tid & 7;

    const u16* row = bg2b + (size_t)i * 64;
    ushort4 beu = *(const ushort4*)(row + l * 4);
    ushort4 gau = *(const ushort4*)(row + 32 + l * 4);
    float4 be = make_float4(bf2f(beu.x), bf2f(beu.y), bf2f(beu.z), bf2f(beu.w));
    float4 ga = make_float4(bf2f(gau.x), bf2f(gau.y), bf2f(gau.z), bf2f(gau.w));

    int base = starts[i], deg = cnt[i];
    const ushort4* xp = (const ushort4*)xlb;
    float4 a0 = make_float4(0.f, 0.f, 0.f, 0.f);
    float4 a1 = make_float4(0.f, 0.f, 0.f, 0.f);
    int e = 0;
    for (; e + 7 < deg; e += 8) {
        int s0 = csr_src[base + e];
        int s1 = csr_src[base + e + 1];
        int s2 = csr_src[base + e + 2];
        int s3 = csr_src[base + e + 3];
        int s4 = csr_src[base + e + 4];
        int s5 = csr_src[base + e + 5];
        int s6 = csr_src[base + e + 6];
        int s7 = csr_src[base + e + 7];
        ushort4 u0 = xp[(size_t)s0 * 8 + l];
        ushort4 u1 = xp[(size_t)s1 * 8 + l];
        ushort4 u2 = xp[(size_t)s2 * 8 + l];
        ushort4 u3 = xp[(size_t)s3 * 8 + l];
        ushort4 u4 = xp[(size_t)s4 * 8 + l];
        ushort4 u5 = xp[(size_t)s5 * 8 + l];
        ushort4 u6 = xp[(size_t)s6 * 8 + l];
        ushort4 u7 = xp[(size_t)s7 * 8 + l];
        EDGE_ACC2(u0, a0) EDGE_ACC2(u1, a1) EDGE_ACC2(u2, a0) EDGE_ACC2(u3, a1)
        EDGE_ACC2(u4, a0) EDGE_ACC2(u5, a1) EDGE_ACC2(u6, a0) EDGE_ACC2(u7, a1)
    }
    for (; e < deg; e++) {
        ushort4 u0 = xp[(size_t)csr_src[base + e] * 8 + l];
        EDGE_ACC2(u0, a0)
    }
    float inv = rcpf(fmaxf((float)deg, 1.0f));
    ushort4 sku = ((const ushort4*)skip2b)[(size_t)i * 8 + l];
    ushort4 o;
    o.x = f2bf(fmaxf(fmaf(a0.x + a1.x, inv, bf2f(sku.x)), 0.f));
    o.y = f2bf(fmaxf(fmaf(a0.y + a1.y, inv, bf2f(sku.y)), 0.f));
    o.z = f2bf(fmaxf(fmaf(a0.z + a1.z, inv, bf2f(sku.z)), 0.f));
    o.w = f2bf(fmaxf(fmaf(a0.w + a1.w, inv, bf2f(sku.w)), 0.f));
    ((ushort4*)h2b)[(size_t)i * 8 + l] = o;
}

// ======================= Layer 3 node-side (scalar, f32 LDS weights — known good) =======================
__global__ __launch_bounds__(256) void k_node3(
    const u16* __restrict__ h2b,
    const float* __restrict__ Wk, const float* __restrict__ bk,
    const float* __restrict__ Wq, const float* __restrict__ bq,
    const float* __restrict__ Wv, const float* __restrict__ bv,
    const float* __restrict__ Wskip, const float* __restrict__ b,
    u16* __restrict__ ek3b, u32* __restrict__ qvb, u16* __restrict__ acc3b)
{
    __shared__ float sWk[1024], sWq[1024], sWv[1024], sWs[1024];
    int t = threadIdx.x;
    for (int idx = t; idx < 1024; idx += 256) {
        sWk[idx] = Wk[idx];
        sWq[idx] = Wq[idx];
        sWv[idx] = Wv[idx];
        sWs[idx] = Wskip[idx];
    }
    __syncthreads();

    int tid = blockIdx.x * 256 + t;
    int i = tid >> 3, l = tid & 7;

    float h[32];
    load_row_bf16(h2b, (size_t)i, h, false);

    float4 bk4 = ((const float4*)bk)[l];
    float4 bq4 = ((const float4*)bq)[l];
    float4 bv4 = ((const float4*)bv)[l];
    float4 bb4 = ((const float4*)b)[l];

    float4 kk = dot4(h, sWk + l * 4, 32);
    ushort4 eku;
    eku.x = f2bf(__expf(-(kk.x + bk4.x)));
    eku.y = f2bf(__expf(-(kk.y + bk4.y)));
    eku.z = f2bf(__expf(-(kk.z + bk4.z)));
    eku.w = f2bf(__expf(-(kk.w + bk4.w)));
    ((ushort4*)ek3b)[(size_t)i * 8 + l] = eku;

    float4 qq = dot4(h, sWq + l * 4, 32);
    float4 vv = dot4(h, sWv + l * 4, 32);
    float eq0 = __expf(-(qq.x + bq4.x));
    float eq1 = __expf(-(qq.y + bq4.y));
    float eq2 = __expf(-(qq.z + bq4.z));
    float eq3 = __expf(-(qq.w + bq4.w));
    vv.x += bv4.x; vv.y += bv4.y; vv.z += bv4.z; vv.w += bv4.w;

    uint4 pk;
    pk.x = (u32)f2bf(eq0) | ((u32)f2bf(eq1) << 16);
    pk.y = (u32)f2bf(eq2) | ((u32)f2bf(eq3) << 16);
    pk.z = (u32)f2bf(vv.x) | ((u32)f2bf(vv.y) << 16);
    pk.w = (u32)f2bf(vv.z) | ((u32)f2bf(vv.w) << 16);
    ((uint4*)qvb)[(size_t)i * 8 + l] = pk;

    float4 ss = dot4(h, sWs + l * 4, 32);
    ushort4 so;
    so.x = f2bf(ss.x + bb4.x);
    so.y = f2bf(ss.y + bb4.y);
    so.z = f2bf(ss.z + bb4.z);
    so.w = f2bf(ss.w + bb4.w);
    ((ushort4*)acc3b)[(size_t)i * 8 + l] = so;
}

// 4 features of one gathered edge: acc += v * rcp(1 + ek*eq)
#define EDGE_ACC(P, ACC)                                                        \
    ACC.x += bf2f((u16)(P.z)) * rcpf(fmaf(ek.x, bf2f((u16)(P.x)), 1.0f));       \
    ACC.y += bf2f((u16)(P.z >> 16)) * rcpf(fmaf(ek.y, bf2f((u16)(P.x >> 16)), 1.0f)); \
    ACC.z += bf2f((u16)(P.w)) * rcpf(fmaf(ek.z, bf2f((u16)(P.y)), 1.0f));       \
    ACC.w += bf2f((u16)(P.w >> 16)) * rcpf(fmaf(ek.w, bf2f((u16)(P.y >> 16)), 1.0f));

// ResGated gather + fused mean-pool
__global__ __launch_bounds__(256) void k_gath3p(
    const int* __restrict__ csr_src, const int* __restrict__ starts,
    const int* __restrict__ cnt,
    const u16* __restrict__ ek3b, const u32* __restrict__ qvb,
    const u16* __restrict__ acc3b, const int* __restrict__ batch,
    float* __restrict__ gsum)
{
    __shared__ float sg[8][32];
    int t = threadIdx.x;
    int tid = blockIdx.x * 256 + t;
    int i = tid >> 3, l = tid & 7;     // grid exact: N*8 == 3125*256

    sg[t >> 5][t & 31] = 0.f;
    int gmin = batch[blockIdx.x * 32];
    __syncthreads();

    ushort4 eku = ((const ushort4*)ek3b)[(size_t)i * 8 + l];
    float4 ek = make_float4(bf2f(eku.x), bf2f(eku.y), bf2f(eku.z), bf2f(eku.w));
    int base = starts[i], deg = cnt[i];
    const uint4* qv = (const uint4*)qvb;
    float4 a0 = make_float4(0.f, 0.f, 0.f, 0.f);
    float4 a1 = make_float4(0.f, 0.f, 0.f, 0.f);
    int e = 0;
    for (; e + 3 < deg; e += 4) {
        int s0 = csr_src[base + e];
        int s1 = csr_src[base + e + 1];
        int s2 = csr_src[base + e + 2];
        int s3 = csr_src[base + e + 3];
        uint4 p0 = qv[(size_t)s0 * 8 + l];
        uint4 p1 = qv[(size_t)s1 * 8 + l];
        uint4 p2 = qv[(size_t)s2 * 8 + l];
        uint4 p3 = qv[(size_t)s3 * 8 + l];
        EDGE_ACC(p0, a0) EDGE_ACC(p1, a1) EDGE_ACC(p2, a0) EDGE_ACC(p3, a1)
    }
    for (; e < deg; e++) {
        uint4 p0 = qv[(size_t)csr_src[base + e] * 8 + l];
        EDGE_ACC(p0, a0)
    }
    ushort4 sku = ((const ushort4*)acc3b)[(size_t)i * 8 + l];
    float4 o = make_float4(bf2f(sku.x) + a0.x + a1.x, bf2f(sku.y) + a0.y + a1.y,
                           bf2f(sku.z) + a0.z + a1.z, bf2f(sku.w) + a0.w + a1.w);

    int g = batch[i];
    int slot = g - gmin;
    if (slot < 8) {
        atomicAdd(&sg[slot][l * 4 + 0], o.x);
        atomicAdd(&sg[slot][l * 4 + 1], o.y);
        atomicAdd(&sg[slot][l * 4 + 2], o.z);
        atomicAdd(&sg[slot][l * 4 + 3], o.w);
    } else {  // defensive fallback
        atomicAdd(&gsum[(size_t)g * 32 + l * 4 + 0], o.x);
        atomicAdd(&gsum[(size_t)g * 32 + l * 4 + 1], o.y);
        atomicAdd(&gsum[(size_t)g * 32 + l * 4 + 2], o.z);
        atomicAdd(&gsum[(size_t)g * 32 + l * 4 + 3], o.w);
    }
    __syncthreads();
    int slot2 = t >> 5, feat = t & 31;
    float v = sg[slot2][feat];
    int gout = gmin + slot2;
    if (v != 0.f && gout < N_GRAPH)
        atomicAdd(&gsum[(size_t)gout * 32 + feat], v);
}

// ======================= classifier (inline segment bounds via bsearch) =======================
__device__ __forceinline__ int lower_bound(const int* __restrict__ a, int key)
{
    int lo = 0, hi = N_NODES;
    while (lo < hi) {
        int mid = (lo + hi) >> 1;
        if (a[mid] < key) lo = mid + 1; else hi = mid;
    }
    return lo;
}

__global__ __launch_bounds__(256) void k_final(
    const float* __restrict__ gsum, const int* __restrict__ batch,
    const float* __restrict__ linW, const float* __restrict__ linb,
    float* __restrict__ out)
{
    int tid = blockIdx.x * 256 + threadIdx.x;
    if (tid >= N_GRAPH * 10) return;
    int g = tid / 10, c = tid % 10;
    int s = lower_bound(batch, g);
    int e = lower_bound(batch, g + 1);
    float inv = rcpf(fmaxf((float)(e - s), 1.0f));
    const float* gr = gsum + (size_t)g * 32;
    float a = 0.f;
#pragma unroll
    for (int k = 0; k < 32; k++) a = fmaf(gr[k], linW[k * 10 + c], a);
    out[tid] = fmaf(a, inv, linb[c]);
}

extern "C" void kernel_launch(void* const* d_in, const int* in_sizes, int n_in,
                              void* d_out, int out_size, void* d_ws, size_t ws_size,
                              hipStream_t stream)
{
    const float* x      = (const float*)d_in[0];
    const int*   ei     = (const int*)d_in[1];
    const int*   batch  = (const int*)d_in[2];
    const float* c1_Wk   = (const float*)d_in[4];
    const float* c1_bk   = (const float*)d_in[5];
    const float* c1_Wq   = (const float*)d_in[6];
    const float* c1_bq   = (const float*)d_in[7];
    const float* c1_Wv   = (const float*)d_in[8];
    const float* c1_bv   = (const float*)d_in[9];
    const float* c1_Wsk  = (const float*)d_in[10];
    const float* c1_b    = (const float*)d_in[11];
    const float* c2_Wlin = (const float*)d_in[12];
    const float* c2_Wfilm= (const float*)d_in[13];
    const float* c2_bfilm= (const float*)d_in[14];
    const float* c2_Wls  = (const float*)d_in[15];
    const float* c2_Wfs  = (const float*)d_in[16];
    const float* c3_Wk   = (const float*)d_in[17];
    const float* c3_bk   = (const float*)d_in[18];
    const float* c3_Wq   = (const float*)d_in[19];
    const float* c3_bq   = (const float*)d_in[20];
    const float* c3_Wv   = (const float*)d_in[21];
    const float* c3_bv   = (const float*)d_in[22];
    const float* c3_Wsk  = (const float*)d_in[23];
    const float* c3_b    = (const float*)d_in[24];
    const float* lin_W   = (const float*)d_in[25];
    const float* lin_b   = (const float*)d_in[26];
    float* out = (float*)d_out;

    const size_t N = N_NODES;

    // ---- workspace layout ----
    int*   gcnt    = (int*)d_ws;                    // 256 (zeroed)
    float* gsum    = (float*)(gcnt + 256);          // G*32 (zeroed, same memset)
    int*   bucketed= (int*)(gsum + N_GRAPH * 32);   // NB*BCAP
    int*   icsr    = bucketed + NB * BCAP;          // E
    int*   istarts = icsr + N_EDGES;                // N
    int*   icnt    = istarts + N;                   // N
    u16*   h1b     = (u16*)(icnt + N);              // N*32 bf16 (reused as h2b)
    u16*   skip2b  = h1b + N * 32;                  // N*32 bf16 (reused as ek3b)
    u16*   bg2b    = skip2b + N * 32;               // N*64 bf16 (reused as qvb)
    u16*   xlb     = bg2b + N * 64;                 // N*32 bf16
    u16*   acc3b   = xlb + N * 32;                  // N*32 bf16
    u16*   wbuf    = acc3b + N * 32;                // 12*512 bf16 frag-ordered weights

    hipMemsetAsync(gcnt, 0, 256 * sizeof(int) + N_GRAPH * 32 * sizeof(float), stream);

    const int TB = 256;
    int gPart  = (N_EDGES + 256 * PEPT - 1) / (256 * PEPT);  // 391
    int gNode8 = (N_NODES * 8) / TB;                         // 3125 exact
    int gN64   = (N_NODES + 63) / 64;                        // 1563
    int gFin   = (N_GRAPH * 10 + TB - 1) / TB;               // 40

    // CSR build + weight prep
    k_partition<<<gPart, TB, 0, stream>>>(ei, gcnt, bucketed);
    k_prepw2<<<1, TB, 0, stream>>>(c2_Wlin, c2_Wfilm, c2_Wls, c2_Wfs, wbuf);
    k_place<<<NB, 512, 0, stream>>>(bucketed, gcnt, icsr, istarts, icnt);

    // Layer 1: x-direct gather, relu'd bf16 out
    k_gath1<<<gNode8, TB, 0, stream>>>(x, icsr, istarts, icnt,
                                       c1_Wk, c1_bk, c1_Wq, c1_bq,
                                       c1_Wv, c1_bv, c1_Wsk, c1_b, h1b);
    // Layer 2 (FiLM): MFMA node-side + gather
    k_node2m<<<gN64, TB, 0, stream>>>(h1b, wbuf, c2_bfilm, skip2b, bg2b, xlb);
    u16* h2b = h1b;
    k_gath2<<<gNode8, TB, 0, stream>>>(icsr, istarts, icnt, bg2b, xlb, skip2b, h2b);
    // Layer 3 (ResGated, scalar node-side) + fused mean-pool
    u16* ek3b = skip2b;
    u32* qvb  = (u32*)bg2b;
    k_node3<<<gNode8, TB, 0, stream>>>(h2b, c3_Wk, c3_bk, c3_Wq, c3_bq,
                                       c3_Wv, c3_bv, c3_Wsk, c3_b,
                                       ek3b, qvb, acc3b);
    k_gath3p<<<gNode8, TB, 0, stream>>>(icsr, istarts, icnt, ek3b, qvb, acc3b,
                                        batch, gsum);
    // classifier
    k_final<<<gFin, TB, 0, stream>>>(gsum, batch, lin_W, lin_b, out);
}

// Round 13
// 281.907 us; speedup vs baseline: 1.2930x; 1.0342x over previous
//
#include <hip/hip_runtime.h>

#define N_NODES 100000
#define N_EDGES 1600000
#define N_GRAPH 1024
#define NB      196      // buckets of 512 nodes
#define BCAP    10240    // bucket capacity (mean 8192, ~22 sigma slack)
#define PEPT    16       // edges per thread in partition

typedef unsigned short u16;
typedef unsigned int   u32;
typedef short bf16x8 __attribute__((ext_vector_type(8)));
typedef float f32x4  __attribute__((ext_vector_type(4)));

__device__ __forceinline__ u16 f2bf(float f) {
    u32 u = __float_as_uint(f);
    u += 0x7FFFu + ((u >> 16) & 1u);
    return (u16)(u >> 16);
}
__device__ __forceinline__ float bf2f(u16 h) { return __uint_as_float(((u32)h) << 16); }
__device__ __forceinline__ float rcpf(float x) { return __builtin_amdgcn_rcpf(x); }
__device__ __forceinline__ float bflo(u32 p) { return __uint_as_float(p << 16); }
__device__ __forceinline__ float bfhi(u32 p) { return __uint_as_float(p & 0xFFFF0000u); }

// ======================= CSR build: bucket partition =======================
__global__ __launch_bounds__(256) void k_partition(const int* __restrict__ ei,
                                                   int* __restrict__ gcnt,
                                                   int* __restrict__ bucketed)
{
    __shared__ int lcnt[NB], gbase[NB], lcur[NB];
    int t = threadIdx.x;
    for (int i = t; i < NB; i += 256) { lcnt[i] = 0; lcur[i] = 0; }
    __syncthreads();

    int ebase = blockIdx.x * (256 * PEPT);
    int pk[PEPT], bk[PEPT];
#pragma unroll
    for (int r = 0; r < PEPT; r++) {
        int e = ebase + r * 256 + t;
        if (e < N_EDGES) {
            int d = ei[N_EDGES + e];
            int s = ei[e];
            int b = d >> 9;
            bk[r] = b;
            pk[r] = ((d & 511) << 17) | s;
            atomicAdd(&lcnt[b], 1);
        } else bk[r] = -1;
    }
    __syncthreads();
    for (int i = t; i < NB; i += 256) gbase[i] = atomicAdd(&gcnt[i], lcnt[i]);
    __syncthreads();
#pragma unroll
    for (int r = 0; r < PEPT; r++) {
        if (bk[r] >= 0) {
            int b = bk[r];
            int pos = gbase[b] + atomicAdd(&lcur[b], 1);
            bucketed[b * BCAP + pos] = pk[r];
        }
    }
}

// one block per bucket: inline scan of gcnt + local CSR in LDS
__global__ __launch_bounds__(512) void k_place(const int* __restrict__ bucketed,
                                               const int* __restrict__ gcnt,
                                               int* __restrict__ csr,
                                               int* __restrict__ starts,
                                               int* __restrict__ cnt)
{
    __shared__ int sb[256];
    __shared__ int scnt[512], sexc[512], scur[512];
    int b = blockIdx.x, t = threadIdx.x;

    if (t < 256) sb[t] = (t < NB) ? gcnt[t] : 0;
    __syncthreads();
#pragma unroll
    for (int off = 1; off < 256; off <<= 1) {
        int u = 0;
        if (t < 256 && t >= off) u = sb[t - off];
        __syncthreads();
        if (t < 256) sb[t] += u;
        __syncthreads();
    }
    int ecnt = gcnt[b];
    int ebase = sb[b] - ecnt;   // exclusive prefix
    const int* bp = bucketed + b * BCAP;

    scnt[t] = 0; scur[t] = 0;
    __syncthreads();
    for (int e = t; e < ecnt; e += 512) atomicAdd(&scnt[bp[e] >> 17], 1);
    __syncthreads();
    int v = scnt[t];
    sexc[t] = v;
    __syncthreads();
#pragma unroll
    for (int off = 1; off < 512; off <<= 1) {
        int u = (t >= off) ? sexc[t - off] : 0;
        __syncthreads();
        sexc[t] += u;
        __syncthreads();
    }
    int excl = sexc[t] - v;
    __syncthreads();
    sexc[t] = excl;
    __syncthreads();

    int node = b * 512 + t;
    if (node < N_NODES) { starts[node] = ebase + excl; cnt[node] = v; }

    for (int e = t; e < ecnt; e += 512) {
        int p = bp[e];
        int ld = p >> 17;
        int pos = ebase + sexc[ld] + atomicAdd(&scur[ld], 1);
        csr[pos] = p & 0x1FFFF;
    }
}

// ======================= Layer 1: ResGated(1 -> 32), x-direct gather =======================
#define EDGE1(XS, ACC) {                                                     \
    ACC.x += fmaf(XS, wv.x, bv4.x) *                                         \
             rcpf(fmaf(ek.x, __expf(-fmaf(XS, wq.x, bq4.x)), 1.0f));         \
    ACC.y += fmaf(XS, wv.y, bv4.y) *                                         \
             rcpf(fmaf(ek.y, __expf(-fmaf(XS, wq.y, bq4.y)), 1.0f));         \
    ACC.z += fmaf(XS, wv.z, bv4.z) *                                         \
             rcpf(fmaf(ek.z, __expf(-fmaf(XS, wq.z, bq4.z)), 1.0f));         \
    ACC.w += fmaf(XS, wv.w, bv4.w) *                                         \
             rcpf(fmaf(ek.w, __expf(-fmaf(XS, wq.w, bq4.w)), 1.0f)); }

// NOTE: stores relu(h1) — layer 2 only ever consumes relu(h1)
__global__ __launch_bounds__(256) void k_gath1(
    const float* __restrict__ x, const int* __restrict__ csr_src,
    const int* __restrict__ starts, const int* __restrict__ cnt,
    const float* __restrict__ Wk, const float* __restrict__ bk,
    const float* __restrict__ Wq, const float* __restrict__ bq,
    const float* __restrict__ Wv, const float* __restrict__ bv,
    const float* __restrict__ Wskip, const float* __restrict__ b,
    u16* __restrict__ h1b)
{
    int tid = blockIdx.x * 256 + threadIdx.x;
    int i = tid >> 3, l = tid & 7;

    float xd = x[i];
    float4 wk = ((const float4*)Wk)[l], bk4 = ((const float4*)bk)[l];
    float4 wq = ((const float4*)Wq)[l], bq4 = ((const float4*)bq)[l];
    float4 wv = ((const float4*)Wv)[l], bv4 = ((const float4*)bv)[l];
    float4 ek;
    ek.x = __expf(-fmaf(xd, wk.x, bk4.x));
    ek.y = __expf(-fmaf(xd, wk.y, bk4.y));
    ek.z = __expf(-fmaf(xd, wk.z, bk4.z));
    ek.w = __expf(-fmaf(xd, wk.w, bk4.w));

    int base = starts[i], deg = cnt[i];
    float4 a0 = make_float4(0.f, 0.f, 0.f, 0.f);
    float4 a1 = make_float4(0.f, 0.f, 0.f, 0.f);
    int e = 0;
    for (; e + 3 < deg; e += 4) {
        int s0 = csr_src[base + e];
        int s1 = csr_src[base + e + 1];
        int s2 = csr_src[base + e + 2];
        int s3 = csr_src[base + e + 3];
        float x0 = x[s0], x1 = x[s1], x2 = x[s2], x3 = x[s3];
        EDGE1(x0, a0) EDGE1(x1, a1) EDGE1(x2, a0) EDGE1(x3, a1)
    }
    for (; e < deg; e++) {
        float x0 = x[csr_src[base + e]];
        EDGE1(x0, a0)
    }
    float4 ws4 = ((const float4*)Wskip)[l];
    float4 bb4 = ((const float4*)b)[l];
    ushort4 o;
    o.x = f2bf(fmaxf(a0.x + a1.x + fmaf(xd, ws4.x, bb4.x), 0.f));
    o.y = f2bf(fmaxf(a0.y + a1.y + fmaf(xd, ws4.y, bb4.y), 0.f));
    o.z = f2bf(fmaxf(a0.z + a1.z + fmaf(xd, ws4.z, bb4.z), 0.f));
    o.w = f2bf(fmaxf(a0.w + a1.w + fmaf(xd, ws4.w, bb4.w), 0.f));
    ((ushort4*)h1b)[(size_t)i * 8 + l] = o;
}

// ======================= weight prep: B-fragment-ordered bf16, 20 tiles =======================
// tiles 0-11 (layer 2): [ls(2) | beta_s(2) | gamma_s(2) | xl(2) | beta(2) | gamma(2)]
// tiles 12-19 (layer 3): [Wk(2) | Wq(2) | Wv(2) | Wskip(2)]
// frag elem: tile t, lane l, j -> B[k=(l>>4)*8+j][n=l&15]
__global__ __launch_bounds__(256) void k_prepw(
    const float* __restrict__ Wlin, const float* __restrict__ Wfilm,
    const float* __restrict__ Wls, const float* __restrict__ Wfs,
    const float* __restrict__ Wk3, const float* __restrict__ Wq3,
    const float* __restrict__ Wv3, const float* __restrict__ Ws3,
    u16* __restrict__ wbuf)
{
    for (int idx = threadIdx.x; idx < 20 * 512; idx += 256) {
        int t = idx >> 9, rem = idx & 511;
        int l = rem >> 3, j = rem & 7;
        int k = ((l >> 4) << 3) + j, n = l & 15;
        float v;
        if      (t < 2)  v = Wls [k * 32 + t * 16 + n];
        else if (t < 4)  v = Wfs [k * 64 + (t - 2) * 16 + n];
        else if (t < 6)  v = Wfs [k * 64 + 32 + (t - 4) * 16 + n];
        else if (t < 8)  v = Wlin[k * 32 + (t - 6) * 16 + n];
        else if (t < 10) v = Wfilm[k * 64 + (t - 8) * 16 + n];
        else if (t < 12) v = Wfilm[k * 64 + 32 + (t - 10) * 16 + n];
        else if (t < 14) v = Wk3[k * 32 + (t - 12) * 16 + n];
        else if (t < 16) v = Wq3[k * 32 + (t - 14) * 16 + n];
        else if (t < 18) v = Wv3[k * 32 + (t - 16) * 16 + n];
        else             v = Ws3[k * 32 + (t - 18) * 16 + n];
        wbuf[idx] = f2bf(v);
    }
}

// ======================= Layer 2 node-side via MFMA =======================
__global__ __launch_bounds__(256) void k_node2m(
    const u16* __restrict__ h1b, const u16* __restrict__ wbuf,
    const float* __restrict__ bfilm,
    u16* __restrict__ skip2b, u16* __restrict__ bg2b, u16* __restrict__ xlb)
{
    int lane = threadIdx.x & 63, w = threadIdx.x >> 6;
    int nb = blockIdx.x * 64 + w * 16;
    int quad = lane >> 4, c = lane & 15;

    int ia = nb + c;
    if (ia >= N_NODES) ia = N_NODES - 1;
    uint4 aq = ((const uint4*)h1b)[(size_t)ia * 4 + quad];
    bf16x8 a = *(bf16x8*)&aq;

    const uint4* wp = (const uint4*)wbuf;
    f32x4 z = {0.f, 0.f, 0.f, 0.f};

    uint4 q0 = wp[0 * 64 + lane], q1 = wp[1 * 64 + lane];
    uint4 q2 = wp[2 * 64 + lane], q3 = wp[3 * 64 + lane];
    uint4 q4 = wp[4 * 64 + lane], q5 = wp[5 * 64 + lane];
    f32x4 dls0 = __builtin_amdgcn_mfma_f32_16x16x32_bf16(a, *(bf16x8*)&q0, z, 0, 0, 0);
    f32x4 dls1 = __builtin_amdgcn_mfma_f32_16x16x32_bf16(a, *(bf16x8*)&q1, z, 0, 0, 0);
    f32x4 dbs0 = __builtin_amdgcn_mfma_f32_16x16x32_bf16(a, *(bf16x8*)&q2, z, 0, 0, 0);
    f32x4 dbs1 = __builtin_amdgcn_mfma_f32_16x16x32_bf16(a, *(bf16x8*)&q3, z, 0, 0, 0);
    f32x4 dgs0 = __builtin_amdgcn_mfma_f32_16x16x32_bf16(a, *(bf16x8*)&q4, z, 0, 0, 0);
    f32x4 dgs1 = __builtin_amdgcn_mfma_f32_16x16x32_bf16(a, *(bf16x8*)&q5, z, 0, 0, 0);
#pragma unroll
    for (int r = 0; r < 4; r++) {
        int node = nb + quad * 4 + r;
        if (node < N_NODES) {
            u16* srow = skip2b + (size_t)node * 32;
            srow[c]      = f2bf(fmaxf(fmaf(dgs0[r], dls0[r], dbs0[r]), 0.f));
            srow[16 + c] = f2bf(fmaxf(fmaf(dgs1[r], dls1[r], dbs1[r]), 0.f));
        }
    }

    uint4 q6 = wp[6 * 64 + lane], q7 = wp[7 * 64 + lane];
    uint4 q8 = wp[8 * 64 + lane], q9 = wp[9 * 64 + lane];
    uint4 qa = wp[10 * 64 + lane], qb = wp[11 * 64 + lane];
    f32x4 dxl0 = __builtin_amdgcn_mfma_f32_16x16x32_bf16(a, *(bf16x8*)&q6, z, 0, 0, 0);
    f32x4 dxl1 = __builtin_amdgcn_mfma_f32_16x16x32_bf16(a, *(bf16x8*)&q7, z, 0, 0, 0);
    f32x4 dbe0 = __builtin_amdgcn_mfma_f32_16x16x32_bf16(a, *(bf16x8*)&q8, z, 0, 0, 0);
    f32x4 dbe1 = __builtin_amdgcn_mfma_f32_16x16x32_bf16(a, *(bf16x8*)&q9, z, 0, 0, 0);
    f32x4 dga0 = __builtin_amdgcn_mfma_f32_16x16x32_bf16(a, *(bf16x8*)&qa, z, 0, 0, 0);
    f32x4 dga1 = __builtin_amdgcn_mfma_f32_16x16x32_bf16(a, *(bf16x8*)&qb, z, 0, 0, 0);

    float bf0 = bfilm[c], bf1 = bfilm[16 + c];
    float bf2 = bfilm[32 + c], bf3 = bfilm[48 + c];
#pragma unroll
    for (int r = 0; r < 4; r++) {
        int node = nb + quad * 4 + r;
        if (node < N_NODES) {
            u16* xrow = xlb + (size_t)node * 32;
            xrow[c]      = f2bf(dxl0[r]);
            xrow[16 + c] = f2bf(dxl1[r]);
            u16* brow = bg2b + (size_t)node * 64;
            brow[c]      = f2bf(dbe0[r] + bf0);
            brow[16 + c] = f2bf(dbe1[r] + bf1);
            brow[32 + c] = f2bf(dga0[r] + bf2);
            brow[48 + c] = f2bf(dga1[r] + bf3);
        }
    }
}

#define EDGE_ACC2(U, ACC)                                   \
    ACC.x += fmaxf(fmaf(ga.x, bf2f(U.x), be.x), 0.f);       \
    ACC.y += fmaxf(fmaf(ga.y, bf2f(U.y), be.y), 0.f);       \
    ACC.z += fmaxf(fmaf(ga.z, bf2f(U.z), be.z), 0.f);       \
    ACC.w += fmaxf(fmaf(ga.w, bf2f(U.w), be.w), 0.f);

// FiLM gather: h2 = relu(skip2 + mean relu(gamma_i*xl_s + beta_i)), bf16 out
__global__ __launch_bounds__(256) void k_gath2(
    const int* __restrict__ csr_src, const int* __restrict__ starts,
    const int* __restrict__ cnt,
    const u16* __restrict__ bg2b, const u16* __restrict__ xlb,
    const u16* __restrict__ skip2b, u16* __restrict__ h2b)
{
    int tid = blockIdx.x * 256 + threadIdx.x;
    int i = tid >> 3, l = tid & 7;

    const u16* row = bg2b + (size_t)i * 64;
    ushort4 beu = *(const ushort4*)(row + l * 4);
    ushort4 gau = *(const ushort4*)(row + 32 + l * 4);
    float4 be = make_float4(bf2f(beu.x), bf2f(beu.y), bf2f(beu.z), bf2f(beu.w));
    float4 ga = make_float4(bf2f(gau.x), bf2f(gau.y), bf2f(gau.z), bf2f(gau.w));

    int base = starts[i], deg = cnt[i];
    const ushort4* xp = (const ushort4*)xlb;
    float4 a0 = make_float4(0.f, 0.f, 0.f, 0.f);
    float4 a1 = make_float4(0.f, 0.f, 0.f, 0.f);
    int e = 0;
    for (; e + 7 < deg; e += 8) {
        int s0 = csr_src[base + e];
        int s1 = csr_src[base + e + 1];
        int s2 = csr_src[base + e + 2];
        int s3 = csr_src[base + e + 3];
        int s4 = csr_src[base + e + 4];
        int s5 = csr_src[base + e + 5];
        int s6 = csr_src[base + e + 6];
        int s7 = csr_src[base + e + 7];
        ushort4 u0 = xp[(size_t)s0 * 8 + l];
        ushort4 u1 = xp[(size_t)s1 * 8 + l];
        ushort4 u2 = xp[(size_t)s2 * 8 + l];
        ushort4 u3 = xp[(size_t)s3 * 8 + l];
        ushort4 u4 = xp[(size_t)s4 * 8 + l];
        ushort4 u5 = xp[(size_t)s5 * 8 + l];
        ushort4 u6 = xp[(size_t)s6 * 8 + l];
        ushort4 u7 = xp[(size_t)s7 * 8 + l];
        EDGE_ACC2(u0, a0) EDGE_ACC2(u1, a1) EDGE_ACC2(u2, a0) EDGE_ACC2(u3, a1)
        EDGE_ACC2(u4, a0) EDGE_ACC2(u5, a1) EDGE_ACC2(u6, a0) EDGE_ACC2(u7, a1)
    }
    for (; e < deg; e++) {
        ushort4 u0 = xp[(size_t)csr_src[base + e] * 8 + l];
        EDGE_ACC2(u0, a0)
    }
    float inv = rcpf(fmaxf((float)deg, 1.0f));
    ushort4 sku = ((const ushort4*)skip2b)[(size_t)i * 8 + l];
    ushort4 o;
    o.x = f2bf(fmaxf(fmaf(a0.x + a1.x, inv, bf2f(sku.x)), 0.f));
    o.y = f2bf(fmaxf(fmaf(a0.y + a1.y, inv, bf2f(sku.y)), 0.f));
    o.z = f2bf(fmaxf(fmaf(a0.z + a1.z, inv, bf2f(sku.z)), 0.f));
    o.w = f2bf(fmaxf(fmaf(a0.w + a1.w, inv, bf2f(sku.w)), 0.f));
    ((ushort4*)h2b)[(size_t)i * 8 + l] = o;
}

// ======================= Layer 3 node-side via MFMA =======================
// wave = 16 nodes; 8 MFMAs (Wk, Wq, Wv, Wskip x 2 tiles each)
// epilogue: ek3b = bf16(exp(-k)); qvb rows = [eq0..3|v0..3] pairs; acc3b = skip
__global__ __launch_bounds__(256) void k_node3m(
    const u16* __restrict__ h2b, const u16* __restrict__ wbuf,
    const float* __restrict__ bk, const float* __restrict__ bq,
    const float* __restrict__ bv, const float* __restrict__ b,
    u16* __restrict__ ek3b, u16* __restrict__ qvbu, u16* __restrict__ acc3b)
{
    int lane = threadIdx.x & 63, w = threadIdx.x >> 6;
    int nb = blockIdx.x * 64 + w * 16;
    int quad = lane >> 4, c = lane & 15;

    int ia = nb + c;
    if (ia >= N_NODES) ia = N_NODES - 1;
    uint4 aq = ((const uint4*)h2b)[(size_t)ia * 4 + quad];
    bf16x8 a = *(bf16x8*)&aq;

    const uint4* wp = (const uint4*)wbuf;
    f32x4 z = {0.f, 0.f, 0.f, 0.f};

    uint4 qk0 = wp[12 * 64 + lane], qk1 = wp[13 * 64 + lane];
    uint4 qq0 = wp[14 * 64 + lane], qq1 = wp[15 * 64 + lane];
    uint4 qv0 = wp[16 * 64 + lane], qv1 = wp[17 * 64 + lane];
    uint4 qs0 = wp[18 * 64 + lane], qs1 = wp[19 * 64 + lane];
    f32x4 dk0 = __builtin_amdgcn_mfma_f32_16x16x32_bf16(a, *(bf16x8*)&qk0, z, 0, 0, 0);
    f32x4 dk1 = __builtin_amdgcn_mfma_f32_16x16x32_bf16(a, *(bf16x8*)&qk1, z, 0, 0, 0);
    f32x4 dq0 = __builtin_amdgcn_mfma_f32_16x16x32_bf16(a, *(bf16x8*)&qq0, z, 0, 0, 0);
    f32x4 dq1 = __builtin_amdgcn_mfma_f32_16x16x32_bf16(a, *(bf16x8*)&qq1, z, 0, 0, 0);
    f32x4 dv0 = __builtin_amdgcn_mfma_f32_16x16x32_bf16(a, *(bf16x8*)&qv0, z, 0, 0, 0);
    f32x4 dv1 = __builtin_amdgcn_mfma_f32_16x16x32_bf16(a, *(bf16x8*)&qv1, z, 0, 0, 0);
    f32x4 ds0 = __builtin_amdgcn_mfma_f32_16x16x32_bf16(a, *(bf16x8*)&qs0, z, 0, 0, 0);
    f32x4 ds1 = __builtin_amdgcn_mfma_f32_16x16x32_bf16(a, *(bf16x8*)&qs1, z, 0, 0, 0);

    float bk0 = bk[c], bk1 = bk[16 + c];
    float bq0 = bq[c], bq1 = bq[16 + c];
    float bv0 = bv[c], bv1 = bv[16 + c];
    float bb0 = b[c],  bb1 = b[16 + c];

    // qvb u16 index within 64-u16 row: feature f -> (f>>2)*8 + (f&3), v at +4
    int qoff0 = ((c >> 2) << 3) + (c & 3);          // feature c
    int qoff1 = 32 + qoff0;                         // feature 16+c
#pragma unroll
    for (int r = 0; r < 4; r++) {
        int node = nb + quad * 4 + r;
        if (node < N_NODES) {
            u16* erow = ek3b + (size_t)node * 32;
            erow[c]      = f2bf(__expf(-(dk0[r] + bk0)));
            erow[16 + c] = f2bf(__expf(-(dk1[r] + bk1)));
            u16* qrow = qvbu + (size_t)node * 64;
            qrow[qoff0]     = f2bf(__expf(-(dq0[r] + bq0)));
            qrow[qoff1]     = f2bf(__expf(-(dq1[r] + bq1)));
            qrow[qoff0 + 4] = f2bf(dv0[r] + bv0);
            qrow[qoff1 + 4] = f2bf(dv1[r] + bv1);
            u16* arow = acc3b + (size_t)node * 32;
            arow[c]      = f2bf(ds0[r] + bb0);
            arow[16 + c] = f2bf(ds1[r] + bb1);
        }
    }
}

// 4 features of one gathered edge: acc += v * rcp(1 + ek*eq)
#define EDGE_ACC(P, ACC)                                                        \
    ACC.x += bf2f((u16)(P.z)) * rcpf(fmaf(ek.x, bf2f((u16)(P.x)), 1.0f));       \
    ACC.y += bf2f((u16)(P.z >> 16)) * rcpf(fmaf(ek.y, bf2f((u16)(P.x >> 16)), 1.0f)); \
    ACC.z += bf2f((u16)(P.w)) * rcpf(fmaf(ek.z, bf2f((u16)(P.y)), 1.0f));       \
    ACC.w += bf2f((u16)(P.w >> 16)) * rcpf(fmaf(ek.w, bf2f((u16)(P.y >> 16)), 1.0f));

// ResGated gather + fused mean-pool
__global__ __launch_bounds__(256) void k_gath3p(
    const int* __restrict__ csr_src, const int* __restrict__ starts,
    const int* __restrict__ cnt,
    const u16* __restrict__ ek3b, const u32* __restrict__ qvb,
    const u16* __restrict__ acc3b, const int* __restrict__ batch,
    float* __restrict__ gsum)
{
    __shared__ float sg[8][32];
    int t = threadIdx.x;
    int tid = blockIdx.x * 256 + t;
    int i = tid >> 3, l = tid & 7;     // grid exact: N*8 == 3125*256

    sg[t >> 5][t & 31] = 0.f;
    int gmin = batch[blockIdx.x * 32];
    __syncthreads();

    ushort4 eku = ((const ushort4*)ek3b)[(size_t)i * 8 + l];
    float4 ek = make_float4(bf2f(eku.x), bf2f(eku.y), bf2f(eku.z), bf2f(eku.w));
    int base = starts[i], deg = cnt[i];
    const uint4* qv = (const uint4*)qvb;
    float4 a0 = make_float4(0.f, 0.f, 0.f, 0.f);
    float4 a1 = make_float4(0.f, 0.f, 0.f, 0.f);
    int e = 0;
    for (; e + 3 < deg; e += 4) {
        int s0 = csr_src[base + e];
        int s1 = csr_src[base + e + 1];
        int s2 = csr_src[base + e + 2];
        int s3 = csr_src[base + e + 3];
        uint4 p0 = qv[(size_t)s0 * 8 + l];
        uint4 p1 = qv[(size_t)s1 * 8 + l];
        uint4 p2 = qv[(size_t)s2 * 8 + l];
        uint4 p3 = qv[(size_t)s3 * 8 + l];
        EDGE_ACC(p0, a0) EDGE_ACC(p1, a1) EDGE_ACC(p2, a0) EDGE_ACC(p3, a1)
    }
    for (; e < deg; e++) {
        uint4 p0 = qv[(size_t)csr_src[base + e] * 8 + l];
        EDGE_ACC(p0, a0)
    }
    ushort4 sku = ((const ushort4*)acc3b)[(size_t)i * 8 + l];
    float4 o = make_float4(bf2f(sku.x) + a0.x + a1.x, bf2f(sku.y) + a0.y + a1.y,
                           bf2f(sku.z) + a0.z + a1.z, bf2f(sku.w) + a0.w + a1.w);

    int g = batch[i];
    int slot = g - gmin;
    if (slot < 8) {
        atomicAdd(&sg[slot][l * 4 + 0], o.x);
        atomicAdd(&sg[slot][l * 4 + 1], o.y);
        atomicAdd(&sg[slot][l * 4 + 2], o.z);
        atomicAdd(&sg[slot][l * 4 + 3], o.w);
    } else {  // defensive fallback
        atomicAdd(&gsum[(size_t)g * 32 + l * 4 + 0], o.x);
        atomicAdd(&gsum[(size_t)g * 32 + l * 4 + 1], o.y);
        atomicAdd(&gsum[(size_t)g * 32 + l * 4 + 2], o.z);
        atomicAdd(&gsum[(size_t)g * 32 + l * 4 + 3], o.w);
    }
    __syncthreads();
    int slot2 = t >> 5, feat = t & 31;
    float v = sg[slot2][feat];
    int gout = gmin + slot2;
    if (v != 0.f && gout < N_GRAPH)
        atomicAdd(&gsum[(size_t)gout * 32 + feat], v);
}

// ======================= classifier (inline segment bounds via bsearch) =======================
__device__ __forceinline__ int lower_bound(const int* __restrict__ a, int key)
{
    int lo = 0, hi = N_NODES;
    while (lo < hi) {
        int mid = (lo + hi) >> 1;
        if (a[mid] < key) lo = mid + 1; else hi = mid;
    }
    return lo;
}

__global__ __launch_bounds__(256) void k_final(
    const float* __restrict__ gsum, const int* __restrict__ batch,
    const float* __restrict__ linW, const float* __restrict__ linb,
    float* __restrict__ out)
{
    int tid = blockIdx.x * 256 + threadIdx.x;
    if (tid >= N_GRAPH * 10) return;
    int g = tid / 10, c = tid % 10;
    int s = lower_bound(batch, g);
    int e = lower_bound(batch, g + 1);
    float inv = rcpf(fmaxf((float)(e - s), 1.0f));
    const float* gr = gsum + (size_t)g * 32;
    float a = 0.f;
#pragma unroll
    for (int k = 0; k < 32; k++) a = fmaf(gr[k], linW[k * 10 + c], a);
    out[tid] = fmaf(a, inv, linb[c]);
}

extern "C" void kernel_launch(void* const* d_in, const int* in_sizes, int n_in,
                              void* d_out, int out_size, void* d_ws, size_t ws_size,
                              hipStream_t stream)
{
    const float* x      = (const float*)d_in[0];
    const int*   ei     = (const int*)d_in[1];
    const int*   batch  = (const int*)d_in[2];
    const float* c1_Wk   = (const float*)d_in[4];
    const float* c1_bk   = (const float*)d_in[5];
    const float* c1_Wq   = (const float*)d_in[6];
    const float* c1_bq   = (const float*)d_in[7];
    const float* c1_Wv   = (const float*)d_in[8];
    const float* c1_bv   = (const float*)d_in[9];
    const float* c1_Wsk  = (const float*)d_in[10];
    const float* c1_b    = (const float*)d_in[11];
    const float* c2_Wlin = (const float*)d_in[12];
    const float* c2_Wfilm= (const float*)d_in[13];
    const float* c2_bfilm= (const float*)d_in[14];
    const float* c2_Wls  = (const float*)d_in[15];
    const float* c2_Wfs  = (const float*)d_in[16];
    const float* c3_Wk   = (const float*)d_in[17];
    const float* c3_bk   = (const float*)d_in[18];
    const float* c3_Wq   = (const float*)d_in[19];
    const float* c3_bq   = (const float*)d_in[20];
    const float* c3_Wv   = (const float*)d_in[21];
    const float* c3_bv   = (const float*)d_in[22];
    const float* c3_Wsk  = (const float*)d_in[23];
    const float* c3_b    = (const float*)d_in[24];
    const float* lin_W   = (const float*)d_in[25];
    const float* lin_b   = (const float*)d_in[26];
    float* out = (float*)d_out;

    const size_t N = N_NODES;

    // ---- workspace layout ----
    int*   gcnt    = (int*)d_ws;                    // 256 (zeroed)
    float* gsum    = (float*)(gcnt + 256);          // G*32 (zeroed, same memset)
    int*   bucketed= (int*)(gsum + N_GRAPH * 32);   // NB*BCAP
    int*   icsr    = bucketed + NB * BCAP;          // E
    int*   istarts = icsr + N_EDGES;                // N
    int*   icnt    = istarts + N;                   // N
    u16*   h1b     = (u16*)(icnt + N);              // N*32 bf16 (reused as h2b)
    u16*   skip2b  = h1b + N * 32;                  // N*32 bf16 (reused as ek3b)
    u16*   bg2b    = skip2b + N * 32;               // N*64 bf16 (reused as qvb)
    u16*   xlb     = bg2b + N * 64;                 // N*32 bf16
    u16*   acc3b   = xlb + N * 32;                  // N*32 bf16
    u16*   wbuf    = acc3b + N * 32;                // 20*512 bf16 frag-ordered weights

    hipMemsetAsync(gcnt, 0, 256 * sizeof(int) + N_GRAPH * 32 * sizeof(float), stream);

    const int TB = 256;
    int gPart  = (N_EDGES + 256 * PEPT - 1) / (256 * PEPT);  // 391
    int gNode8 = (N_NODES * 8) / TB;                         // 3125 exact
    int gN64   = (N_NODES + 63) / 64;                        // 1563
    int gFin   = (N_GRAPH * 10 + TB - 1) / TB;               // 40

    // CSR build + weight prep
    k_partition<<<gPart, TB, 0, stream>>>(ei, gcnt, bucketed);
    k_prepw<<<1, TB, 0, stream>>>(c2_Wlin, c2_Wfilm, c2_Wls, c2_Wfs,
                                  c3_Wk, c3_Wq, c3_Wv, c3_Wsk, wbuf);
    k_place<<<NB, 512, 0, stream>>>(bucketed, gcnt, icsr, istarts, icnt);

    // Layer 1: x-direct gather, relu'd bf16 out
    k_gath1<<<gNode8, TB, 0, stream>>>(x, icsr, istarts, icnt,
                                       c1_Wk, c1_bk, c1_Wq, c1_bq,
                                       c1_Wv, c1_bv, c1_Wsk, c1_b, h1b);
    // Layer 2 (FiLM): MFMA node-side + gather
    k_node2m<<<gN64, TB, 0, stream>>>(h1b, wbuf, c2_bfilm, skip2b, bg2b, xlb);
    u16* h2b = h1b;
    k_gath2<<<gNode8, TB, 0, stream>>>(icsr, istarts, icnt, bg2b, xlb, skip2b, h2b);
    // Layer 3 (ResGated): MFMA node-side + fused mean-pool gather
    u16* ek3b = skip2b;
    u16* qvbu = bg2b;
    k_node3m<<<gN64, TB, 0, stream>>>(h2b, wbuf, c3_bk, c3_bq, c3_bv, c3_b,
                                      ek3b, qvbu, acc3b);
    k_gath3p<<<gNode8, TB, 0, stream>>>(icsr, istarts, icnt, ek3b, (u32*)qvbu,
                                        acc3b, batch, gsum);
    // classifier
    k_final<<<gFin, TB, 0, stream>>>(gsum, batch, lin_W, lin_b, out);
}